// Round 3
// baseline (136.807 us; speedup 1.0000x reference)
//
#include <hip/hip_runtime.h>

// Problem constants (x: [3, 64, 64] float32)
#define C_DIM   3
#define H_DIM   64
#define W_DIM   64
#define HW      (H_DIM * W_DIM)          // 4096
#define N_TOT   (C_DIM * HW)             // 12288
#define PREP_T  1024
#define PER     (N_TOT / PREP_T)         // 12
#define FILL_T  256
#define F4_PER_ROW (N_TOT / 4)           // 3072
#define F4_PER_THR (F4_PER_ROW / FILL_T) // 12
#define EPS_F   0.1f

typedef float f4 __attribute__((ext_vector_type(4)));  // native vector for nontemporal builtins

// Workspace layout (floats/ints, all 4B):
//   center : N_TOT floats            (ws + 0)
//   errmap : N_TOT+1 floats          (ws + N_TOT)
//   colmap : N_TOT+1 ints            (ws + 2*N_TOT + 1)

// Prep: compute center/err, block-wide scan of mask -> 1-based rows,
// build inverse map (row -> col, err), write terms.
__global__ __launch_bounds__(PREP_T) void zono_prep(
        const float* __restrict__ x,
        float* __restrict__ terms,     // N x 2 as float32
        float* __restrict__ center,
        float* __restrict__ errmap,
        int*   __restrict__ colmap)
{
    const int tid  = threadIdx.x;
    const int base = tid * PER;

    float cen[PER];
    float ev[PER];
    bool  m[PER];
    int   cnt = 0;

#pragma unroll
    for (int i = 0; i < PER; ++i) {
        float xv = x[base + i];
        float a  = fmaxf(EPS_F - xv, 0.0f) * 0.5f;
        float b  = fmaxf(xv - (1.0f - EPS_F), 0.0f) * 0.5f;
        cen[i]   = xv + a - b;
        float e  = EPS_F - a - b;
        ev[i]    = e;
        m[i]     = (e >= 0.0f);
        cnt     += m[i] ? 1 : 0;
        center[base + i] = cen[i];
        colmap[base + i + 1] = -1;     // default: row has no nonzero
    }

    // Block-wide inclusive scan (Hillis-Steele) over per-thread mask counts.
    __shared__ int sh[PREP_T];
    sh[tid] = cnt;
    __syncthreads();
    for (int off = 1; off < PREP_T; off <<= 1) {
        int t = (tid >= off) ? sh[tid - off] : 0;
        __syncthreads();
        sh[tid] += t;
        __syncthreads();
    }
    int run = sh[tid] - cnt;  // exclusive prefix for this thread's chunk
    // (the colmap default writes above are ordered before these scatters by
    //  the scan's __syncthreads barriers)

#pragma unroll
    for (int i = 0; i < PER; ++i) {
        const int idx = base + i;
        float rowf, fidxf;
        if (m[i]) {
            ++run;                      // 1-based cumsum value
            colmap[run] = idx;
            errmap[run] = ev[i];
            rowf  = (float)run;
            fidxf = (float)(idx / HW);
        } else {
            rowf  = -1.0f;
            fidxf = -1.0f;
        }
        terms[2 * idx + 0] = rowf;
        terms[2 * idx + 1] = fidxf;
    }
}

// Fill: one workgroup per output row; streaming float4 stores.
__global__ __launch_bounds__(FILL_T) void zono_fill(
        float* __restrict__ zono,
        const float* __restrict__ center,
        const float* __restrict__ errmap,
        const int*   __restrict__ colmap)
{
    const int row = blockIdx.x;
    f4* dst = (f4*)(zono + (size_t)row * N_TOT);

    if (row == 0) {
        const f4* src = (const f4*)center;
#pragma unroll
        for (int k = 0; k < F4_PER_THR; ++k) {
            int j = threadIdx.x + k * FILL_T;
            __builtin_nontemporal_store(src[j], &dst[j]);
        }
    } else {
        const int   col = colmap[row];          // -1 if row empty
        const float ev  = errmap[row];          // unused when col < 0
        const int patch_j = col >> 2;           // -1 never matches j
        const int patch_l = col & 3;
        const f4 z = {0.f, 0.f, 0.f, 0.f};
#pragma unroll
        for (int k = 0; k < F4_PER_THR; ++k) {
            int j = threadIdx.x + k * FILL_T;
            f4 v = z;
            v[patch_l] = (j == patch_j) ? ev : v[patch_l];
            __builtin_nontemporal_store(v, &dst[j]);
        }
    }
}

extern "C" void kernel_launch(void* const* d_in, const int* in_sizes, int n_in,
                              void* d_out, int out_size, void* d_ws, size_t ws_size,
                              hipStream_t stream) {
    const float* x = (const float*)d_in[0];
    float* out = (float*)d_out;

    const size_t zono_elems = (size_t)(N_TOT + 1) * (size_t)N_TOT;  // 151,007,232
    float* terms = out + zono_elems;

    float* center = (float*)d_ws;
    float* errmap = center + N_TOT;
    int*   colmap = (int*)(errmap + N_TOT + 1);

    zono_prep<<<1, PREP_T, 0, stream>>>(x, terms, center, errmap, colmap);
    zono_fill<<<N_TOT + 1, FILL_T, 0, stream>>>(out, center, errmap, colmap);
}